// Round 9
// baseline (1251.839 us; speedup 1.0000x reference)
//
#include <hip/hip_runtime.h>
#include <math.h>

#define NNODES 100000
#define NEDGES 200000
#define HD 64
#define NP2 250000
#define NP3 500000
#define NG 2048
#define NCLS 10
#define NFEAT 18
#define EFEAT 18

typedef short short8v __attribute__((ext_vector_type(8)));
typedef float f32x4 __attribute__((ext_vector_type(4)));

__device__ __forceinline__ unsigned short bf16r(float a) {
    unsigned u = __builtin_bit_cast(unsigned, a);
    return (unsigned short)((u + 0x7FFFu + ((u >> 16) & 1u)) >> 16);
}
// pack two f32 -> bf16 pair (RNE), a low, b high
__device__ __forceinline__ unsigned bfpack(float a, float b) {
    unsigned ua = __builtin_bit_cast(unsigned, a);
    unsigned ub = __builtin_bit_cast(unsigned, b);
    ua = (ua + 0x7FFFu + ((ua >> 16) & 1u)) >> 16;
    ub = (ub + 0x7FFFu + ((ub >> 16) & 1u)) & 0xFFFF0000u;
    return ua | ub;
}

// ---------------------------------------------------------------------------
// prep_all: zero hsum1+hsum2 and st..pooled; bsum = b_ih+b_hh; Bp frag blob.
// Bp[((kc*16 + nt)*64 + l)*8 + j] = bf16(B[k][n]),
//   k = kc*32 + (l>>4)*8 + j,  nt = jh*4 + qg,  n = qg*64 + 16*jh + (l&15).
// ---------------------------------------------------------------------------
__global__ void prep_all(const float* __restrict__ b_ih, const float* __restrict__ b_hh,
                         const float* __restrict__ w_ih, const float* __restrict__ w_hh,
                         float* __restrict__ bsum, unsigned short* __restrict__ Bp,
                         float* __restrict__ zeroA, long nzeroA4,
                         float* __restrict__ zeroB, long nzeroB) {
    long gid = (long)blockIdx.x * 256 + threadIdx.x;
    long stride = (long)gridDim.x * 256;
    float4 z = make_float4(0.f, 0.f, 0.f, 0.f);
    for (long i = gid; i < nzeroA4; i += stride) ((float4*)zeroA)[i] = z;
    for (long i = gid; i < nzeroB; i += stride) zeroB[i] = 0.f;
    for (long i = gid; i < 6 * 16 * 64 * 8; i += stride) {
        int kc = (int)(i >> 13);
        int rem = (int)(i & 8191);
        int nt = rem >> 9;
        int rem2 = rem & 511;
        int l = rem2 >> 3, j = rem2 & 7;
        int c = l & 15, q = l >> 4;
        int jh = nt >> 2, qg = nt & 3;
        int k = kc * 32 + q * 8 + j;
        int n = qg * 64 + 16 * jh + c;
        float f = (k < 128) ? w_ih[n * 128 + k] : w_hh[n * 64 + (k - 128)];
        Bp[i] = bf16r(f);
    }
    if (gid < 256) bsum[gid] = b_ih[gid] + b_hh[gid];
}

// ---------------------------------------------------------------------------
// Combined encoder, 4 cols/thread: unit = (row, col-quad).
// rows < NNODES -> node enc (W0 f32 + W0b bf16); else edge enc (eab bf16).
// ---------------------------------------------------------------------------
__global__ void encode_all(const float* __restrict__ X, const float* __restrict__ Wf,
                           const float* __restrict__ bf,
                           const float* __restrict__ Ea, const float* __restrict__ Wb,
                           const float* __restrict__ bb,
                           float* __restrict__ W0, unsigned short* __restrict__ W0b,
                           unsigned short* __restrict__ eab) {
    long gid = (long)blockIdx.x * 256 + threadIdx.x;
    if (gid >= (long)(NNODES + NEDGES) * 16) return;
    long r = gid >> 4;
    int col = (int)(gid & 15) * 4;
    if (r < NNODES) {
        float4 acc = *(const float4*)(bf + col);
        const float* xr = X + r * NFEAT;
        for (int k = 0; k < NFEAT; ++k) {
            float xv = xr[k];
            float4 wv = *(const float4*)(Wf + k * 64 + col);
            acc.x += xv * wv.x; acc.y += xv * wv.y;
            acc.z += xv * wv.z; acc.w += xv * wv.w;
        }
        *(float4*)(W0 + r * 64 + col) = acc;
        uint2 u; u.x = bfpack(acc.x, acc.y); u.y = bfpack(acc.z, acc.w);
        *(uint2*)(W0b + r * 64 + col) = u;
    } else {
        long r2 = r - NNODES;
        float4 acc = *(const float4*)(bb + col);
        const float* xr = Ea + r2 * EFEAT;
        for (int k = 0; k < EFEAT; ++k) {
            float xv = xr[k];
            float4 wv = *(const float4*)(Wb + k * 64 + col);
            acc.x += xv * wv.x; acc.y += xv * wv.y;
            acc.z += xv * wv.z; acc.w += xv * wv.w;
        }
        uint2 u; u.x = bfpack(acc.x, acc.y); u.y = bfpack(acc.z, acc.w);
        *(uint2*)(eab + r2 * 64 + col) = u;
    }
}

// ---------------------------------------------------------------------------
// MFMA LSTM path conv, register-resident B, m-split accumulators (32 AGPR,
// two disjoint lifetimes) + double-buffered h rows -> target 3 blocks/CU.
// Al (bf16): [p=64][k], stride 264; k 0..63 node, 64..127 edge,
// 128..191 h buf0, 192..255 h buf1.  Step s reads h buf (s&1), writes
// buf ((s+1)&1); that buffer's last readers finished before the previous
// iteration's closing barrier, and half-0 activation rows (0..31) are
// disjoint from half-1 MFMA read rows (32..63) -> no hazards.
// Per step: 2 barriers, 24 ds_read_b128, 96 MFMA.  Step 0 skips chunks 2..5.
// ---------------------------------------------------------------------------
template <int L>
__global__ __launch_bounds__(256, 3)
void conv_mfma(const unsigned short* __restrict__ xb, const unsigned short* __restrict__ eab,
               const int* __restrict__ paths, const int* __restrict__ ei,
               const unsigned short* __restrict__ Bp, const float* __restrict__ bsum,
               float* __restrict__ hsum, int P) {
    __shared__ unsigned short Al[64 * 264];

    const int t = threadIdx.x;
    const int w = t >> 6, lane = t & 63;
    const int c = lane & 15, q = lane >> 4;
    const int pl = t >> 2, gq = t & 3;
    const long pg = (long)blockIdx.x * 64 + pl;
    const int pc = (pg < P) ? (int)pg : P - 1;

    short8v Bfr[6][4];
#pragma unroll
    for (int kc = 0; kc < 6; ++kc)
#pragma unroll
        for (int qg = 0; qg < 4; ++qg)
            Bfr[kc][qg] = *(const short8v*)&Bp[(((kc * 16) + (w * 4 + qg)) * 64 + lane) * 8];

    float breg[4];
#pragma unroll
    for (int qg = 0; qg < 4; ++qg) breg[qg] = bsum[qg * 64 + 16 * w + c];

    float creg[16];
#pragma unroll
    for (int i = 0; i < 16; ++i) creg[i] = 0.f;

    uint4 nu0, nu1, ev0, ev1;
    {
        int node = paths[pc * L + 0];
        const uint4* s4 = (const uint4*)(xb + (size_t)node * HD);
        nu0 = s4[2 * gq]; nu1 = s4[2 * gq + 1];
    }

    for (int step = 0; step < L; ++step) {
        *(uint4*)&Al[pl * 264 + gq * 16] = nu0;
        *(uint4*)&Al[pl * 264 + gq * 16 + 8] = nu1;
        if (step > 0) {
            *(uint4*)&Al[pl * 264 + 64 + gq * 16] = ev0;
            *(uint4*)&Al[pl * 264 + 64 + gq * 16 + 8] = ev1;
        }
        __syncthreads();   // gathers + prev h-writes visible

        if (step + 1 < L) {
            int node = paths[pc * L + step + 1];
            const uint4* s4 = (const uint4*)(xb + (size_t)node * HD);
            nu0 = s4[2 * gq]; nu1 = s4[2 * gq + 1];
            int e = ei[pc * (L - 1) + step];
            const uint4* e4 = (const uint4*)(eab + (size_t)e * HD);
            ev0 = e4[2 * gq]; ev1 = e4[2 * gq + 1];
        }

        const int hoff = 128 + (step & 1) * 64;        // h read (cur)
        const int hwr = 128 + ((step + 1) & 1) * 64;   // h write (next)

        auto do_half = [&](int h2) {
            f32x4 acc2[2][4];
#pragma unroll
            for (int m = 0; m < 2; ++m)
#pragma unroll
                for (int qg = 0; qg < 4; ++qg) {
                    f32x4 v; v[0] = breg[qg]; v[1] = breg[qg];
                    v[2] = breg[qg]; v[3] = breg[qg];
                    acc2[m][qg] = v;
                }
            auto chunk = [&](int kc, int koff) {
#pragma unroll
                for (int m = 0; m < 2; ++m) {
                    short8v af = *(const short8v*)
                        &Al[((h2 * 2 + m) * 16 + c) * 264 + koff + q * 8];
#pragma unroll
                    for (int qg = 0; qg < 4; ++qg)
                        acc2[m][qg] = __builtin_amdgcn_mfma_f32_16x16x32_bf16(
                            af, Bfr[kc][qg], acc2[m][qg], 0, 0, 0);
                }
            };
            if (step == 0) {
                chunk(0, 0); chunk(1, 32);
            } else {
                chunk(0, 0); chunk(1, 32); chunk(2, 64); chunk(3, 96);
                chunk(4, hoff); chunk(5, hoff + 32);
            }
#pragma unroll
            for (int m = 0; m < 2; ++m) {
                const int mt = h2 * 2 + m;
#pragma unroll
                for (int r = 0; r < 4; ++r) {
                    float gi = acc2[m][0][r], gf = acc2[m][1][r];
                    float gg = acc2[m][2][r], go = acc2[m][3][r];
                    float ea = __expf(-gf), eb = __expf(-gi);
                    float ed = __expf(-2.f * gg), eo = __expf(-go);
                    float pa = 1.f + ea, pb = 1.f + eb, pd = 1.f + ed;
                    float cn = (creg[mt * 4 + r] * pb * pd + (1.f - ed) * pa) *
                               __builtin_amdgcn_rcpf(pa * pb * pd);
                    creg[mt * 4 + r] = cn;
                    float et = __expf(-2.f * cn);
                    float hn = (1.f - et) *
                               __builtin_amdgcn_rcpf((1.f + eo) * (1.f + et));
                    if (step < L - 1) {
                        Al[(mt * 16 + q * 4 + r) * 264 + hwr + 16 * w + c] = bf16r(hn);
                    } else {
                        long pr = (long)blockIdx.x * 64 + mt * 16 + q * 4 + r;
                        if (pr < P) {
                            int node = paths[pr * L + (L - 1)];
                            atomicAdd(hsum + (size_t)node * HD + 16 * w + c, hn);
                        }
                    }
                }
            }
        };
        do_half(0);
        do_half(1);
        __syncthreads();   // all MFMA A-reads done before next gather
    }
}

// ---------------------------------------------------------------------------
// Per-column sum / sumsq over rows (for BN stats)
// ---------------------------------------------------------------------------
__global__ void col_stats(const float* __restrict__ X, int nrows, float* __restrict__ out) {
    int col = threadIdx.x & 63, rg = threadIdx.x >> 6;
    float s = 0.f, q = 0.f;
    long stride = (long)gridDim.x * 4;
    for (long r = (long)blockIdx.x * 4 + rg; r < nrows; r += stride) {
        float v = X[r * 64 + col];
        s += v;
        q += v * v;
    }
    __shared__ float red[2][256];
    red[0][threadIdx.x] = s;
    red[1][threadIdx.x] = q;
    __syncthreads();
    if (threadIdx.x < 64) {
        int c = threadIdx.x;
        float ss = red[0][c] + red[0][c + 64] + red[0][c + 128] + red[0][c + 192];
        float qq = red[1][c] + red[1][c + 64] + red[1][c + 128] + red[1][c + 192];
        atomicAdd(out + c, ss);
        atomicAdd(out + 64 + c, qq);
    }
}

// per-thread BN affine from raw stats
__device__ __forceinline__ void bn_affine(const float* stats, const float* g,
                                          const float* b, int col,
                                          float& a, float& c) {
    const float inv = 1.0f / (float)NNODES;
    float mean = stats[col] * inv;
    float var = stats[64 + col] * inv - mean * mean;
    a = g[col] * rsqrtf(var + 1e-5f);
    c = b[col] - mean * a;
}

// ---------------------------------------------------------------------------
// Y[n][j] = sum_k inAct(X[n][k]*a[k]+c[k]) * W[k][j] + bias[j]
// BN affine from raw stats; optional fused col-stats of Y.
// ---------------------------------------------------------------------------
template <bool INRELU, bool STATS>
__global__ __launch_bounds__(256)
void gemm64(const float* __restrict__ X, const float* __restrict__ stats_in,
            const float* __restrict__ bn_gm, const float* __restrict__ bn_bt,
            const float* __restrict__ W, const float* __restrict__ bias,
            float* __restrict__ Y, float* stats, int nrows) {
    __shared__ float Xs[64 * 64];
    __shared__ float red[2][256];
    const int t = threadIdx.x;
    const int col = t & 63, rg = t >> 6;
    const long r0 = (long)blockIdx.x * 64;

    float a = 1.f, c = 0.f;
    if (stats_in) bn_affine(stats_in, bn_gm, bn_bt, col, a, c);

    for (int i = 0; i < 16; ++i) {
        int rl = rg * 16 + i;
        long r = r0 + rl;
        float v = (r < nrows) ? X[r * 64 + col] : 0.f;
        v = v * a + c;
        if (INRELU) v = fmaxf(v, 0.f);
        Xs[rl * 64 + col] = v;
    }
    __syncthreads();

    float wreg[64];
#pragma unroll
    for (int k = 0; k < 64; ++k) wreg[k] = W[k * 64 + col];
    float bs = bias[col];
    float ssum = 0.f, ssq = 0.f;

    for (int i = 0; i < 16; ++i) {
        int rl = rg * 16 + i;
        long r = r0 + rl;
        const float4* xs4 = (const float4*)(Xs + rl * 64);
        float acc = bs;
#pragma unroll
        for (int k4 = 0; k4 < 16; ++k4) {
            float4 xv = xs4[k4];
            acc += xv.x * wreg[4 * k4] + xv.y * wreg[4 * k4 + 1] +
                   xv.z * wreg[4 * k4 + 2] + xv.w * wreg[4 * k4 + 3];
        }
        if (r < nrows) {
            Y[r * 64 + col] = acc;
            ssum += acc;
            ssq += acc * acc;
        }
    }
    if (STATS) {
        red[0][t] = ssum;
        red[1][t] = ssq;
        __syncthreads();
        if (t < 64) {
            float s = red[0][t] + red[0][t + 64] + red[0][t + 128] + red[0][t + 192];
            float qq = red[1][t] + red[1][t + 64] + red[1][t + 128] + red[1][t + 192];
            atomicAdd(stats + t, s);
            atomicAdd(stats + 64 + t, qq);
        }
    }
}

// conv1 epilogue (float4): W1 = relu(BN(W1)); Winb = bf16(0.75*W0 - 0.25*W1)
__global__ void bn_apply1(float* __restrict__ W1, const float* __restrict__ stats,
                          const float* __restrict__ g, const float* __restrict__ b,
                          const float* __restrict__ W0, unsigned short* __restrict__ Winb) {
    long gid = (long)blockIdx.x * 256 + threadIdx.x;
    if (gid >= (long)NNODES * 16) return;
    long r = gid >> 4;
    int col = (int)(gid & 15) * 4;
    float a0, c0, a1, c1, a2, c2, a3, c3;
    bn_affine(stats, g, b, col + 0, a0, c0);
    bn_affine(stats, g, b, col + 1, a1, c1);
    bn_affine(stats, g, b, col + 2, a2, c2);
    bn_affine(stats, g, b, col + 3, a3, c3);
    float4 v = *(const float4*)(W1 + r * 64 + col);
    v.x = fmaxf(v.x * a0 + c0, 0.f);
    v.y = fmaxf(v.y * a1 + c1, 0.f);
    v.z = fmaxf(v.z * a2 + c2, 0.f);
    v.w = fmaxf(v.w * a3 + c3, 0.f);
    *(float4*)(W1 + r * 64 + col) = v;
    float4 w0 = *(const float4*)(W0 + r * 64 + col);
    uint2 u;
    u.x = bfpack(0.75f * w0.x - 0.25f * v.x, 0.75f * w0.y - 0.25f * v.y);
    u.y = bfpack(0.75f * w0.z - 0.25f * v.z, 0.75f * w0.w - 0.25f * v.w);
    *(uint2*)(Winb + r * 64 + col) = u;
}

// conv2 epilogue fused with attention dots (float4):
// W2 = relu(BN(W2)); atts[h] += sum W0*W1; atts[64+h] += sum W0*W2
__global__ void bn_apply_att(float* __restrict__ W2, const float* __restrict__ stats,
                             const float* __restrict__ g, const float* __restrict__ b,
                             const float* __restrict__ W0, const float* __restrict__ W1,
                             float* __restrict__ atts, int n) {
    int cq = threadIdx.x & 15, rg = threadIdx.x >> 4;
    int col = cq * 4;
    float a0, c0, a1, c1, a2, c2, a3, c3;
    bn_affine(stats, g, b, col + 0, a0, c0);
    bn_affine(stats, g, b, col + 1, a1, c1);
    bn_affine(stats, g, b, col + 2, a2, c2);
    bn_affine(stats, g, b, col + 3, a3, c3);
    float4 s1 = make_float4(0.f, 0.f, 0.f, 0.f);
    float4 s2 = make_float4(0.f, 0.f, 0.f, 0.f);
    long stride = (long)gridDim.x * 16;
    for (long r = (long)blockIdx.x * 16 + rg; r < n; r += stride) {
        long gid = r * 64 + col;
        float4 v = *(const float4*)(W2 + gid);
        v.x = fmaxf(v.x * a0 + c0, 0.f);
        v.y = fmaxf(v.y * a1 + c1, 0.f);
        v.z = fmaxf(v.z * a2 + c2, 0.f);
        v.w = fmaxf(v.w * a3 + c3, 0.f);
        *(float4*)(W2 + gid) = v;
        float4 q0 = *(const float4*)(W0 + gid);
        float4 w1 = *(const float4*)(W1 + gid);
        s1.x += q0.x * w1.x; s1.y += q0.y * w1.y;
        s1.z += q0.z * w1.z; s1.w += q0.w * w1.w;
        s2.x += q0.x * v.x; s2.y += q0.y * v.y;
        s2.z += q0.z * v.z; s2.w += q0.w * v.w;
    }
    __shared__ float4 red4[2][256];
    red4[0][threadIdx.x] = s1;
    red4[1][threadIdx.x] = s2;
    __syncthreads();
    if (threadIdx.x < 16) {
        int t = threadIdx.x;
        float4 A = make_float4(0.f, 0.f, 0.f, 0.f);
        float4 B = make_float4(0.f, 0.f, 0.f, 0.f);
        for (int j = 0; j < 16; ++j) {
            float4 x = red4[0][j * 16 + t];
            float4 y = red4[1][j * 16 + t];
            A.x += x.x; A.y += x.y; A.z += x.z; A.w += x.w;
            B.x += y.x; B.y += y.y; B.z += y.z; B.w += y.w;
        }
        atomicAdd(atts + 4 * t + 0, A.x);
        atomicAdd(atts + 4 * t + 1, A.y);
        atomicAdd(atts + 4 * t + 2, A.z);
        atomicAdd(atts + 4 * t + 3, A.w);
        atomicAdd(atts + 64 + 4 * t + 0, B.x);
        atomicAdd(atts + 64 + 4 * t + 1, B.y);
        atomicAdd(atts + 64 + 4 * t + 2, B.z);
        atomicAdd(atts + 64 + 4 * t + 3, B.w);
    }
}

// single wave: normalize scores, dot w_att, softmax over the 2 -> watt[0..1]
__global__ void att_softmax(const float* __restrict__ atts, const float* __restrict__ w_att,
                            const float* __restrict__ b_att, float* __restrict__ watt) {
    int h = threadIdx.x;  // 0..63
    float z[2];
    for (int k = 0; k < 2; ++k) {
        float s = atts[64 * k + h];
        float mn = s, mx = s;
        for (int off = 32; off > 0; off >>= 1) {
            mn = fminf(mn, __shfl_down(mn, off));
            mx = fmaxf(mx, __shfl_down(mx, off));
        }
        mn = __shfl(mn, 0);
        mx = __shfl(mx, 0);
        float sn = (s - mn) / (mx - mn + 1e-6f);
        float d = sn * w_att[h];
        for (int off = 32; off > 0; off >>= 1) d += __shfl_down(d, off);
        z[k] = __shfl(d, 0) + b_att[0];
    }
    if (h == 0) {
        float m = fmaxf(z[0], z[1]);
        float e0 = expf(z[0] - m), e1 = expf(z[1] - m);
        float inv = 1.0f / (e0 + e1);
        watt[0] = e0 * inv;
        watt[1] = e1 * inv;
    }
}

// rep = W0 + w1*W1 + w2*W2, segmented scatter (batch sorted), float4 cols.
#define PROWS 256
__global__ void pool_rep(const float* __restrict__ W0, const float* __restrict__ W1,
                         const float* __restrict__ W2, const float* __restrict__ watt,
                         const int* __restrict__ batch, float* __restrict__ pooled, int n) {
    int cq = threadIdx.x & 15, rg = threadIdx.x >> 4;
    int col = cq * 4;
    long r0 = (long)blockIdx.x * PROWS;
    float w1s = watt[0], w2s = watt[1];
    float4 acc = make_float4(0.f, 0.f, 0.f, 0.f);
    int curg = -1;
    for (int i = rg; i < PROWS; i += 16) {
        long r = r0 + i;
        if (r >= n) break;
        int g = batch[r];
        long gid = r * 64 + col;
        float4 a = *(const float4*)(W0 + gid);
        float4 b = *(const float4*)(W1 + gid);
        float4 d = *(const float4*)(W2 + gid);
        float4 rep;
        rep.x = a.x + w1s * b.x + w2s * d.x;
        rep.y = a.y + w1s * b.y + w2s * d.y;
        rep.z = a.z + w1s * b.z + w2s * d.z;
        rep.w = a.w + w1s * b.w + w2s * d.w;
        if (g != curg) {
            if (curg >= 0) {
                float* p = pooled + (size_t)curg * 64 + col;
                atomicAdd(p + 0, acc.x); atomicAdd(p + 1, acc.y);
                atomicAdd(p + 2, acc.z); atomicAdd(p + 3, acc.w);
            }
            curg = g;
            acc = make_float4(0.f, 0.f, 0.f, 0.f);
        }
        acc.x += rep.x; acc.y += rep.y; acc.z += rep.z; acc.w += rep.w;
    }
    if (curg >= 0) {
        float* p = pooled + (size_t)curg * 64 + col;
        atomicAdd(p + 0, acc.x); atomicAdd(p + 1, acc.y);
        atomicAdd(p + 2, acc.z); atomicAdd(p + 3, acc.w);
    }
}

// fused head: lin1 = relu(relu(pooled) @ w_l1 + b_l1); out = lin1 @ w_l2 + b_l2
__global__ __launch_bounds__(256)
void head_kernel(const float* __restrict__ pooled, const float* __restrict__ w_l1,
                 const float* __restrict__ b_l1, const float* __restrict__ w_l2,
                 const float* __restrict__ b_l2, float* __restrict__ out) {
    __shared__ float Xs[64 * 64];
    __shared__ float Ys[64 * 65];
    const int t = threadIdx.x;
    const int col = t & 63, rg = t >> 6;
    const int r0 = blockIdx.x * 64;

    for (int i = 0; i < 16; ++i) {
        int rl = rg * 16 + i;
        Xs[rl * 64 + col] = fmaxf(pooled[(size_t)(r0 + rl) * 64 + col], 0.f);
    }
    __syncthreads();

    float wreg[64];
#pragma unroll
    for (int k = 0; k < 64; ++k) wreg[k] = w_l1[k * 64 + col];
    float bs = b_l1[col];

    for (int i = 0; i < 16; ++i) {
        int rl = rg * 16 + i;
        const float4* xs4 = (const float4*)(Xs + rl * 64);
        float acc = bs;
#pragma unroll
        for (int k4 = 0; k4 < 16; ++k4) {
            float4 xv = xs4[k4];
            acc += xv.x * wreg[4 * k4] + xv.y * wreg[4 * k4 + 1] +
                   xv.z * wreg[4 * k4 + 2] + xv.w * wreg[4 * k4 + 3];
        }
        Ys[rl * 65 + col] = fmaxf(acc, 0.f);
    }
    __syncthreads();

    for (int idx = t; idx < 64 * NCLS; idx += 256) {
        int row = idx / NCLS, j = idx - row * NCLS;
        float acc = b_l2[j];
#pragma unroll
        for (int k = 0; k < 64; ++k) acc += Ys[row * 65 + k] * w_l2[k * NCLS + j];
        out[(size_t)(r0 + row) * NCLS + j] = acc;
    }
}

// ---------------------------------------------------------------------------
extern "C" void kernel_launch(void* const* d_in, const int* in_sizes, int n_in,
                              void* d_out, int out_size, void* d_ws, size_t ws_size,
                              hipStream_t stream) {
    const float* x         = (const float*)d_in[0];
    const float* edge_attr = (const float*)d_in[1];
    const int*   paths2    = (const int*)d_in[2];
    const int*   ei2       = (const int*)d_in[3];
    const int*   paths3    = (const int*)d_in[4];
    const int*   ei3       = (const int*)d_in[5];
    const int*   batch     = (const int*)d_in[6];
    const float* w_feat    = (const float*)d_in[7];
    const float* b_feat    = (const float*)d_in[8];
    const float* w_bond    = (const float*)d_in[9];
    const float* b_bond    = (const float*)d_in[10];
    const float* w_ih      = (const float*)d_in[11];
    const float* w_hh      = (const float*)d_in[12];
    const float* b_ih      = (const float*)d_in[13];
    const float* b_hh      = (const float*)d_in[14];
    const float* bn_g      = (const float*)d_in[15];
    const float* bn_b      = (const float*)d_in[16];
    const float* mlp_w1    = (const float*)d_in[17];
    const float* mlp_b1    = (const float*)d_in[18];
    const float* bn1_g     = (const float*)d_in[19];
    const float* bn1_b     = (const float*)d_in[20];
    const float* mlp_w2    = (const float*)d_in[21];
    const float* mlp_b2    = (const float*)d_in[22];
    const float* bn2_g     = (const float*)d_in[23];
    const float* bn2_b     = (const float*)d_in[24];
    const float* w_att     = (const float*)d_in[25];
    const float* b_att     = (const float*)d_in[26];
    const float* w_l1      = (const float*)d_in[27];
    const float* b_l1      = (const float*)d_in[28];
    const float* w_l2      = (const float*)d_in[29];
    const float* b_l2      = (const float*)d_in[30];

    const size_t N64 = (size_t)NNODES * 64;
    float* ws = (float*)d_ws;
    float* W0     = ws;                               // N*64 f32
    float* W1     = W0 + N64;                         // N*64 f32
    float* W2     = W1 + N64;                         // N*64 f32
    float* Wtmp   = W2 + N64;                         // N*64 f32
    float* hsum1  = Wtmp + N64;                       // N*64 f32
    float* hsum2  = hsum1 + N64;                      // N*64 f32
    unsigned short* W0b  = (unsigned short*)(hsum2 + N64);  // N*64 bf16
    unsigned short* Winb = W0b + N64;                       // N*64 bf16
    unsigned short* eab  = Winb + N64;                      // E*64 bf16
    unsigned short* Bp   = eab + (size_t)NEDGES * 64;       // 6*16*64*8 bf16
    float* bsum   = (float*)(Bp + 6 * 16 * 64 * 8);   // 256
    float* st     = bsum + 256;                       // 768
    float* atts   = st + 768;                         // 128
    float* watt   = atts + 128;                       // 64 (2 used)
    float* pooled = watt + 64;                        // G*64

    // ---- prep: zero hsum1+hsum2 and st..pooled; bsum; Bp
    {
        long nzeroA4 = (long)(2 * N64) / 4;
        long nzeroB = 768 + 128 + 64 + (long)NG * 64;
        prep_all<<<2048, 256, 0, stream>>>(b_ih, b_hh, w_ih, w_hh, bsum, Bp,
                                           hsum1, nzeroA4, st, nzeroB);
    }
    encode_all<<<(int)(((size_t)(NNODES + NEDGES) * 16 + 255) / 256), 256, 0, stream>>>(
        x, w_feat, b_feat, edge_attr, w_bond, b_bond, W0, W0b, eab);

    // ---------------- conv 1 (L=2) ----------------
    conv_mfma<2><<<(NP2 + 63) / 64, 256, 0, stream>>>(W0b, eab, paths2, ei2, Bp, bsum, hsum1, NP2);

    col_stats<<<1024, 256, 0, stream>>>(hsum1, NNODES, st + 0);
    gemm64<false, true><<<(NNODES + 63) / 64, 256, 0, stream>>>(hsum1, st + 0, bn_g + 0, bn_b + 0, mlp_w1, mlp_b1, Wtmp, st + 128, NNODES);
    gemm64<true, true><<<(NNODES + 63) / 64, 256, 0, stream>>>(Wtmp, st + 128, bn1_g + 0, bn1_b + 0, mlp_w2, mlp_b2, W1, st + 256, NNODES);
    bn_apply1<<<(int)(((size_t)NNODES * 16 + 255) / 256), 256, 0, stream>>>(W1, st + 256, bn2_g + 0, bn2_b + 0, W0, Winb);

    // ---------------- conv 2 (L=3) ----------------
    conv_mfma<3><<<(NP3 + 63) / 64, 256, 0, stream>>>(Winb, eab, paths3, ei3, Bp, bsum, hsum2, NP3);

    col_stats<<<1024, 256, 0, stream>>>(hsum2, NNODES, st + 384);
    gemm64<false, true><<<(NNODES + 63) / 64, 256, 0, stream>>>(hsum2, st + 384, bn_g + 64, bn_b + 64, mlp_w1 + 4096, mlp_b1 + 64, Wtmp, st + 512, NNODES);
    gemm64<true, true><<<(NNODES + 63) / 64, 256, 0, stream>>>(Wtmp, st + 512, bn1_g + 64, bn1_b + 64, mlp_w2 + 4096, mlp_b2 + 64, W2, st + 640, NNODES);
    bn_apply_att<<<1024, 256, 0, stream>>>(W2, st + 640, bn2_g + 64, bn2_b + 64, W0, W1, atts, NNODES);

    // ---------------- attention + pooling + head ----------------
    att_softmax<<<1, 64, 0, stream>>>(atts, w_att, b_att, watt);
    pool_rep<<<(NNODES + PROWS - 1) / PROWS, 256, 0, stream>>>(W0, W1, W2, watt, batch, pooled, NNODES);
    head_kernel<<<NG / 64, 256, 0, stream>>>(pooled, w_l1, b_l1, w_l2, b_l2, (float*)d_out);
}

// Round 10
// 991.390 us; speedup vs baseline: 1.2627x; 1.2627x over previous
//
#include <hip/hip_runtime.h>
#include <math.h>

#define NNODES 100000
#define NEDGES 200000
#define HD 64
#define NP2 250000
#define NP3 500000
#define NG 2048
#define NCLS 10
#define NFEAT 18
#define EFEAT 18

typedef short short8v __attribute__((ext_vector_type(8)));
typedef float f32x4 __attribute__((ext_vector_type(4)));

__device__ __forceinline__ unsigned short bf16r(float a) {
    unsigned u = __builtin_bit_cast(unsigned, a);
    return (unsigned short)((u + 0x7FFFu + ((u >> 16) & 1u)) >> 16);
}
// pack two f32 -> bf16 pair (RNE), a low, b high
__device__ __forceinline__ unsigned bfpack(float a, float b) {
    unsigned ua = __builtin_bit_cast(unsigned, a);
    unsigned ub = __builtin_bit_cast(unsigned, b);
    ua = (ua + 0x7FFFu + ((ua >> 16) & 1u)) >> 16;
    ub = (ub + 0x7FFFu + ((ub >> 16) & 1u)) & 0xFFFF0000u;
    return ua | ub;
}

// ---------------------------------------------------------------------------
// prep_all: zero hsum1+hsum2 and st..pooled; bsum = b_ih+b_hh; Bp frag blob.
// Bp[((kc*16 + nt)*64 + l)*8 + j] = bf16(B[k][n]),
//   k = kc*32 + (l>>4)*8 + j,  nt = jh*4 + qg,  n = qg*64 + 16*jh + (l&15).
// ---------------------------------------------------------------------------
__global__ void prep_all(const float* __restrict__ b_ih, const float* __restrict__ b_hh,
                         const float* __restrict__ w_ih, const float* __restrict__ w_hh,
                         float* __restrict__ bsum, unsigned short* __restrict__ Bp,
                         float* __restrict__ zeroA, long nzeroA4,
                         float* __restrict__ zeroB, long nzeroB) {
    long gid = (long)blockIdx.x * 256 + threadIdx.x;
    long stride = (long)gridDim.x * 256;
    float4 z = make_float4(0.f, 0.f, 0.f, 0.f);
    for (long i = gid; i < nzeroA4; i += stride) ((float4*)zeroA)[i] = z;
    for (long i = gid; i < nzeroB; i += stride) zeroB[i] = 0.f;
    for (long i = gid; i < 6 * 16 * 64 * 8; i += stride) {
        int kc = (int)(i >> 13);
        int rem = (int)(i & 8191);
        int nt = rem >> 9;
        int rem2 = rem & 511;
        int l = rem2 >> 3, j = rem2 & 7;
        int c = l & 15, q = l >> 4;
        int jh = nt >> 2, qg = nt & 3;
        int k = kc * 32 + q * 8 + j;
        int n = qg * 64 + 16 * jh + c;
        float f = (k < 128) ? w_ih[n * 128 + k] : w_hh[n * 64 + (k - 128)];
        Bp[i] = bf16r(f);
    }
    if (gid < 256) bsum[gid] = b_ih[gid] + b_hh[gid];
}

// ---------------------------------------------------------------------------
// Combined encoder, 4 cols/thread: unit = (row, col-quad).
// rows < NNODES -> node enc (W0 f32 + W0b bf16); else edge enc (eab bf16).
// ---------------------------------------------------------------------------
__global__ void encode_all(const float* __restrict__ X, const float* __restrict__ Wf,
                           const float* __restrict__ bf,
                           const float* __restrict__ Ea, const float* __restrict__ Wb,
                           const float* __restrict__ bb,
                           float* __restrict__ W0, unsigned short* __restrict__ W0b,
                           unsigned short* __restrict__ eab) {
    long gid = (long)blockIdx.x * 256 + threadIdx.x;
    if (gid >= (long)(NNODES + NEDGES) * 16) return;
    long r = gid >> 4;
    int col = (int)(gid & 15) * 4;
    if (r < NNODES) {
        float4 acc = *(const float4*)(bf + col);
        const float* xr = X + r * NFEAT;
        for (int k = 0; k < NFEAT; ++k) {
            float xv = xr[k];
            float4 wv = *(const float4*)(Wf + k * 64 + col);
            acc.x += xv * wv.x; acc.y += xv * wv.y;
            acc.z += xv * wv.z; acc.w += xv * wv.w;
        }
        *(float4*)(W0 + r * 64 + col) = acc;
        uint2 u; u.x = bfpack(acc.x, acc.y); u.y = bfpack(acc.z, acc.w);
        *(uint2*)(W0b + r * 64 + col) = u;
    } else {
        long r2 = r - NNODES;
        float4 acc = *(const float4*)(bb + col);
        const float* xr = Ea + r2 * EFEAT;
        for (int k = 0; k < EFEAT; ++k) {
            float xv = xr[k];
            float4 wv = *(const float4*)(Wb + k * 64 + col);
            acc.x += xv * wv.x; acc.y += xv * wv.y;
            acc.z += xv * wv.z; acc.w += xv * wv.w;
        }
        uint2 u; u.x = bfpack(acc.x, acc.y); u.y = bfpack(acc.z, acc.w);
        *(uint2*)(eab + r2 * 64 + col) = u;
    }
}

// ---------------------------------------------------------------------------
// MFMA LSTM path conv (R6-proven): register-resident B, monolithic acc[4][4],
// next-step gather prefetch, 2 waves/SIMD (the occupancy ceiling for this
// register budget: Bfr 96 + acc 64 + creg/prefetch/misc ~= 180 unified regs;
// do NOT request 3 waves/SIMD - it spills ~1.5 GB of scratch per dispatch,
// measured R9).  Per step: 2 barriers, 24 ds_read_b128, 96 MFMA.
// ---------------------------------------------------------------------------
template <int L>
__global__ __launch_bounds__(256, 2)
void conv_mfma(const unsigned short* __restrict__ xb, const unsigned short* __restrict__ eab,
               const int* __restrict__ paths, const int* __restrict__ ei,
               const unsigned short* __restrict__ Bp, const float* __restrict__ bsum,
               float* __restrict__ hsum, int P) {
    __shared__ unsigned short Al[64 * 200];

    const int t = threadIdx.x;
    const int w = t >> 6, lane = t & 63;
    const int c = lane & 15, q = lane >> 4;
    const int pl = t >> 2, gq = t & 3;
    const long pg = (long)blockIdx.x * 64 + pl;
    const int pc = (pg < P) ? (int)pg : P - 1;

    short8v Bfr[6][4];
#pragma unroll
    for (int kc = 0; kc < 6; ++kc)
#pragma unroll
        for (int qg = 0; qg < 4; ++qg)
            Bfr[kc][qg] = *(const short8v*)&Bp[(((kc * 16) + (w * 4 + qg)) * 64 + lane) * 8];

    float breg[4];
#pragma unroll
    for (int qg = 0; qg < 4; ++qg) breg[qg] = bsum[qg * 64 + 16 * w + c];

    float creg[16];
#pragma unroll
    for (int i = 0; i < 16; ++i) creg[i] = 0.f;

    f32x4 acc[4][4];

    uint4 nu0, nu1, ev0, ev1;
    {
        int node = paths[pc * L + 0];
        const uint4* s4 = (const uint4*)(xb + (size_t)node * HD);
        nu0 = s4[2 * gq]; nu1 = s4[2 * gq + 1];
    }

    for (int step = 0; step < L; ++step) {
        *(uint4*)&Al[pl * 200 + gq * 16] = nu0;
        *(uint4*)&Al[pl * 200 + gq * 16 + 8] = nu1;
        if (step > 0) {
            *(uint4*)&Al[pl * 200 + 64 + gq * 16] = ev0;
            *(uint4*)&Al[pl * 200 + 64 + gq * 16 + 8] = ev1;
        }
#pragma unroll
        for (int mt = 0; mt < 4; ++mt)
#pragma unroll
            for (int qg = 0; qg < 4; ++qg) {
                f32x4 v; v[0] = breg[qg]; v[1] = breg[qg]; v[2] = breg[qg]; v[3] = breg[qg];
                acc[mt][qg] = v;
            }
        __syncthreads();   // gather (and prev-step h) visible to all waves

        if (step + 1 < L) {
            int node = paths[pc * L + step + 1];
            const uint4* s4 = (const uint4*)(xb + (size_t)node * HD);
            nu0 = s4[2 * gq]; nu1 = s4[2 * gq + 1];
            int e = ei[pc * (L - 1) + step];
            const uint4* e4 = (const uint4*)(eab + (size_t)e * HD);
            ev0 = e4[2 * gq]; ev1 = e4[2 * gq + 1];
        }

        auto chunk = [&](int kc, int koff) {
#pragma unroll
            for (int mt = 0; mt < 4; ++mt) {
                short8v af = *(const short8v*)&Al[(mt * 16 + c) * 200 + koff + q * 8];
#pragma unroll
                for (int qg = 0; qg < 4; ++qg)
                    acc[mt][qg] = __builtin_amdgcn_mfma_f32_16x16x32_bf16(
                        af, Bfr[kc][qg], acc[mt][qg], 0, 0, 0);
            }
        };
        if (step == 0) {
            chunk(0, 0); chunk(1, 32);
        } else {
            chunk(0, 0); chunk(1, 32); chunk(2, 64);
            chunk(3, 96); chunk(4, 128); chunk(5, 160);
        }
        __syncthreads();   // all A reads done before h-writeback / next gather

#pragma unroll
        for (int mt = 0; mt < 4; ++mt) {
#pragma unroll
            for (int r = 0; r < 4; ++r) {
                float gi = acc[mt][0][r], gf = acc[mt][1][r];
                float gg = acc[mt][2][r], go = acc[mt][3][r];
                float ea = __expf(-gf), eb = __expf(-gi);
                float ed = __expf(-2.f * gg), eo = __expf(-go);
                float pa = 1.f + ea, pb = 1.f + eb, pd = 1.f + ed;
                float cn = (creg[mt * 4 + r] * pb * pd + (1.f - ed) * pa) *
                           __builtin_amdgcn_rcpf(pa * pb * pd);
                creg[mt * 4 + r] = cn;
                float et = __expf(-2.f * cn);
                float hn = (1.f - et) *
                           __builtin_amdgcn_rcpf((1.f + eo) * (1.f + et));
                if (step < L - 1) {
                    Al[(mt * 16 + q * 4 + r) * 200 + 128 + 16 * w + c] = bf16r(hn);
                } else {
                    long pr = (long)blockIdx.x * 64 + mt * 16 + q * 4 + r;
                    if (pr < P) {
                        int node = paths[pr * L + (L - 1)];
                        atomicAdd(hsum + (size_t)node * HD + 16 * w + c, hn);
                    }
                }
            }
        }
    }
}

// ---------------------------------------------------------------------------
// Per-column sum / sumsq over rows (for BN stats)
// ---------------------------------------------------------------------------
__global__ void col_stats(const float* __restrict__ X, int nrows, float* __restrict__ out) {
    int col = threadIdx.x & 63, rg = threadIdx.x >> 6;
    float s = 0.f, q = 0.f;
    long stride = (long)gridDim.x * 4;
    for (long r = (long)blockIdx.x * 4 + rg; r < nrows; r += stride) {
        float v = X[r * 64 + col];
        s += v;
        q += v * v;
    }
    __shared__ float red[2][256];
    red[0][threadIdx.x] = s;
    red[1][threadIdx.x] = q;
    __syncthreads();
    if (threadIdx.x < 64) {
        int c = threadIdx.x;
        float ss = red[0][c] + red[0][c + 64] + red[0][c + 128] + red[0][c + 192];
        float qq = red[1][c] + red[1][c + 64] + red[1][c + 128] + red[1][c + 192];
        atomicAdd(out + c, ss);
        atomicAdd(out + 64 + c, qq);
    }
}

// per-thread BN affine from raw stats
__device__ __forceinline__ void bn_affine(const float* stats, const float* g,
                                          const float* b, int col,
                                          float& a, float& c) {
    const float inv = 1.0f / (float)NNODES;
    float mean = stats[col] * inv;
    float var = stats[64 + col] * inv - mean * mean;
    a = g[col] * rsqrtf(var + 1e-5f);
    c = b[col] - mean * a;
}

// ---------------------------------------------------------------------------
// Y[n][j] = sum_k inAct(X[n][k]*a[k]+c[k]) * W[k][j] + bias[j]
// BN affine from raw stats; optional fused col-stats of Y.
// ---------------------------------------------------------------------------
template <bool INRELU, bool STATS>
__global__ __launch_bounds__(256)
void gemm64(const float* __restrict__ X, const float* __restrict__ stats_in,
            const float* __restrict__ bn_gm, const float* __restrict__ bn_bt,
            const float* __restrict__ W, const float* __restrict__ bias,
            float* __restrict__ Y, float* stats, int nrows) {
    __shared__ float Xs[64 * 64];
    __shared__ float red[2][256];
    const int t = threadIdx.x;
    const int col = t & 63, rg = t >> 6;
    const long r0 = (long)blockIdx.x * 64;

    float a = 1.f, c = 0.f;
    if (stats_in) bn_affine(stats_in, bn_gm, bn_bt, col, a, c);

    for (int i = 0; i < 16; ++i) {
        int rl = rg * 16 + i;
        long r = r0 + rl;
        float v = (r < nrows) ? X[r * 64 + col] : 0.f;
        v = v * a + c;
        if (INRELU) v = fmaxf(v, 0.f);
        Xs[rl * 64 + col] = v;
    }
    __syncthreads();

    float wreg[64];
#pragma unroll
    for (int k = 0; k < 64; ++k) wreg[k] = W[k * 64 + col];
    float bs = bias[col];
    float ssum = 0.f, ssq = 0.f;

    for (int i = 0; i < 16; ++i) {
        int rl = rg * 16 + i;
        long r = r0 + rl;
        const float4* xs4 = (const float4*)(Xs + rl * 64);
        float acc = bs;
#pragma unroll
        for (int k4 = 0; k4 < 16; ++k4) {
            float4 xv = xs4[k4];
            acc += xv.x * wreg[4 * k4] + xv.y * wreg[4 * k4 + 1] +
                   xv.z * wreg[4 * k4 + 2] + xv.w * wreg[4 * k4 + 3];
        }
        if (r < nrows) {
            Y[r * 64 + col] = acc;
            ssum += acc;
            ssq += acc * acc;
        }
    }
    if (STATS) {
        red[0][t] = ssum;
        red[1][t] = ssq;
        __syncthreads();
        if (t < 64) {
            float s = red[0][t] + red[0][t + 64] + red[0][t + 128] + red[0][t + 192];
            float qq = red[1][t] + red[1][t + 64] + red[1][t + 128] + red[1][t + 192];
            atomicAdd(stats + t, s);
            atomicAdd(stats + 64 + t, qq);
        }
    }
}

// conv1 epilogue (float4): W1 = relu(BN(W1)); Winb = bf16(0.75*W0 - 0.25*W1)
__global__ void bn_apply1(float* __restrict__ W1, const float* __restrict__ stats,
                          const float* __restrict__ g, const float* __restrict__ b,
                          const float* __restrict__ W0, unsigned short* __restrict__ Winb) {
    long gid = (long)blockIdx.x * 256 + threadIdx.x;
    if (gid >= (long)NNODES * 16) return;
    long r = gid >> 4;
    int col = (int)(gid & 15) * 4;
    float a0, c0, a1, c1, a2, c2, a3, c3;
    bn_affine(stats, g, b, col + 0, a0, c0);
    bn_affine(stats, g, b, col + 1, a1, c1);
    bn_affine(stats, g, b, col + 2, a2, c2);
    bn_affine(stats, g, b, col + 3, a3, c3);
    float4 v = *(const float4*)(W1 + r * 64 + col);
    v.x = fmaxf(v.x * a0 + c0, 0.f);
    v.y = fmaxf(v.y * a1 + c1, 0.f);
    v.z = fmaxf(v.z * a2 + c2, 0.f);
    v.w = fmaxf(v.w * a3 + c3, 0.f);
    *(float4*)(W1 + r * 64 + col) = v;
    float4 w0 = *(const float4*)(W0 + r * 64 + col);
    uint2 u;
    u.x = bfpack(0.75f * w0.x - 0.25f * v.x, 0.75f * w0.y - 0.25f * v.y);
    u.y = bfpack(0.75f * w0.z - 0.25f * v.z, 0.75f * w0.w - 0.25f * v.w);
    *(uint2*)(Winb + r * 64 + col) = u;
}

// conv2 epilogue fused with attention dots (float4):
// W2 = relu(BN(W2)); atts[h] += sum W0*W1; atts[64+h] += sum W0*W2
__global__ void bn_apply_att(float* __restrict__ W2, const float* __restrict__ stats,
                             const float* __restrict__ g, const float* __restrict__ b,
                             const float* __restrict__ W0, const float* __restrict__ W1,
                             float* __restrict__ atts, int n) {
    int cq = threadIdx.x & 15, rg = threadIdx.x >> 4;
    int col = cq * 4;
    float a0, c0, a1, c1, a2, c2, a3, c3;
    bn_affine(stats, g, b, col + 0, a0, c0);
    bn_affine(stats, g, b, col + 1, a1, c1);
    bn_affine(stats, g, b, col + 2, a2, c2);
    bn_affine(stats, g, b, col + 3, a3, c3);
    float4 s1 = make_float4(0.f, 0.f, 0.f, 0.f);
    float4 s2 = make_float4(0.f, 0.f, 0.f, 0.f);
    long stride = (long)gridDim.x * 16;
    for (long r = (long)blockIdx.x * 16 + rg; r < n; r += stride) {
        long gid = r * 64 + col;
        float4 v = *(const float4*)(W2 + gid);
        v.x = fmaxf(v.x * a0 + c0, 0.f);
        v.y = fmaxf(v.y * a1 + c1, 0.f);
        v.z = fmaxf(v.z * a2 + c2, 0.f);
        v.w = fmaxf(v.w * a3 + c3, 0.f);
        *(float4*)(W2 + gid) = v;
        float4 q0 = *(const float4*)(W0 + gid);
        float4 w1 = *(const float4*)(W1 + gid);
        s1.x += q0.x * w1.x; s1.y += q0.y * w1.y;
        s1.z += q0.z * w1.z; s1.w += q0.w * w1.w;
        s2.x += q0.x * v.x; s2.y += q0.y * v.y;
        s2.z += q0.z * v.z; s2.w += q0.w * v.w;
    }
    __shared__ float4 red4[2][256];
    red4[0][threadIdx.x] = s1;
    red4[1][threadIdx.x] = s2;
    __syncthreads();
    if (threadIdx.x < 16) {
        int t = threadIdx.x;
        float4 A = make_float4(0.f, 0.f, 0.f, 0.f);
        float4 B = make_float4(0.f, 0.f, 0.f, 0.f);
        for (int j = 0; j < 16; ++j) {
            float4 x = red4[0][j * 16 + t];
            float4 y = red4[1][j * 16 + t];
            A.x += x.x; A.y += x.y; A.z += x.z; A.w += x.w;
            B.x += y.x; B.y += y.y; B.z += y.z; B.w += y.w;
        }
        atomicAdd(atts + 4 * t + 0, A.x);
        atomicAdd(atts + 4 * t + 1, A.y);
        atomicAdd(atts + 4 * t + 2, A.z);
        atomicAdd(atts + 4 * t + 3, A.w);
        atomicAdd(atts + 64 + 4 * t + 0, B.x);
        atomicAdd(atts + 64 + 4 * t + 1, B.y);
        atomicAdd(atts + 64 + 4 * t + 2, B.z);
        atomicAdd(atts + 64 + 4 * t + 3, B.w);
    }
}

// single wave: normalize scores, dot w_att, softmax over the 2 -> watt[0..1]
__global__ void att_softmax(const float* __restrict__ atts, const float* __restrict__ w_att,
                            const float* __restrict__ b_att, float* __restrict__ watt) {
    int h = threadIdx.x;  // 0..63
    float z[2];
    for (int k = 0; k < 2; ++k) {
        float s = atts[64 * k + h];
        float mn = s, mx = s;
        for (int off = 32; off > 0; off >>= 1) {
            mn = fminf(mn, __shfl_down(mn, off));
            mx = fmaxf(mx, __shfl_down(mx, off));
        }
        mn = __shfl(mn, 0);
        mx = __shfl(mx, 0);
        float sn = (s - mn) / (mx - mn + 1e-6f);
        float d = sn * w_att[h];
        for (int off = 32; off > 0; off >>= 1) d += __shfl_down(d, off);
        z[k] = __shfl(d, 0) + b_att[0];
    }
    if (h == 0) {
        float m = fmaxf(z[0], z[1]);
        float e0 = expf(z[0] - m), e1 = expf(z[1] - m);
        float inv = 1.0f / (e0 + e1);
        watt[0] = e0 * inv;
        watt[1] = e1 * inv;
    }
}

// rep = W0 + w1*W1 + w2*W2, segmented scatter (batch sorted), float4 cols.
#define PROWS 256
__global__ void pool_rep(const float* __restrict__ W0, const float* __restrict__ W1,
                         const float* __restrict__ W2, const float* __restrict__ watt,
                         const int* __restrict__ batch, float* __restrict__ pooled, int n) {
    int cq = threadIdx.x & 15, rg = threadIdx.x >> 4;
    int col = cq * 4;
    long r0 = (long)blockIdx.x * PROWS;
    float w1s = watt[0], w2s = watt[1];
    float4 acc = make_float4(0.f, 0.f, 0.f, 0.f);
    int curg = -1;
    for (int i = rg; i < PROWS; i += 16) {
        long r = r0 + i;
        if (r >= n) break;
        int g = batch[r];
        long gid = r * 64 + col;
        float4 a = *(const float4*)(W0 + gid);
        float4 b = *(const float4*)(W1 + gid);
        float4 d = *(const float4*)(W2 + gid);
        float4 rep;
        rep.x = a.x + w1s * b.x + w2s * d.x;
        rep.y = a.y + w1s * b.y + w2s * d.y;
        rep.z = a.z + w1s * b.z + w2s * d.z;
        rep.w = a.w + w1s * b.w + w2s * d.w;
        if (g != curg) {
            if (curg >= 0) {
                float* p = pooled + (size_t)curg * 64 + col;
                atomicAdd(p + 0, acc.x); atomicAdd(p + 1, acc.y);
                atomicAdd(p + 2, acc.z); atomicAdd(p + 3, acc.w);
            }
            curg = g;
            acc = make_float4(0.f, 0.f, 0.f, 0.f);
        }
        acc.x += rep.x; acc.y += rep.y; acc.z += rep.z; acc.w += rep.w;
    }
    if (curg >= 0) {
        float* p = pooled + (size_t)curg * 64 + col;
        atomicAdd(p + 0, acc.x); atomicAdd(p + 1, acc.y);
        atomicAdd(p + 2, acc.z); atomicAdd(p + 3, acc.w);
    }
}

// fused head: lin1 = relu(relu(pooled) @ w_l1 + b_l1); out = lin1 @ w_l2 + b_l2
__global__ __launch_bounds__(256)
void head_kernel(const float* __restrict__ pooled, const float* __restrict__ w_l1,
                 const float* __restrict__ b_l1, const float* __restrict__ w_l2,
                 const float* __restrict__ b_l2, float* __restrict__ out) {
    __shared__ float Xs[64 * 64];
    __shared__ float Ys[64 * 65];
    const int t = threadIdx.x;
    const int col = t & 63, rg = t >> 6;
    const int r0 = blockIdx.x * 64;

    for (int i = 0; i < 16; ++i) {
        int rl = rg * 16 + i;
        Xs[rl * 64 + col] = fmaxf(pooled[(size_t)(r0 + rl) * 64 + col], 0.f);
    }
    __syncthreads();

    float wreg[64];
#pragma unroll
    for (int k = 0; k < 64; ++k) wreg[k] = w_l1[k * 64 + col];
    float bs = b_l1[col];

    for (int i = 0; i < 16; ++i) {
        int rl = rg * 16 + i;
        const float4* xs4 = (const float4*)(Xs + rl * 64);
        float acc = bs;
#pragma unroll
        for (int k4 = 0; k4 < 16; ++k4) {
            float4 xv = xs4[k4];
            acc += xv.x * wreg[4 * k4] + xv.y * wreg[4 * k4 + 1] +
                   xv.z * wreg[4 * k4 + 2] + xv.w * wreg[4 * k4 + 3];
        }
        Ys[rl * 65 + col] = fmaxf(acc, 0.f);
    }
    __syncthreads();

    for (int idx = t; idx < 64 * NCLS; idx += 256) {
        int row = idx / NCLS, j = idx - row * NCLS;
        float acc = b_l2[j];
#pragma unroll
        for (int k = 0; k < 64; ++k) acc += Ys[row * 65 + k] * w_l2[k * NCLS + j];
        out[(size_t)(r0 + row) * NCLS + j] = acc;
    }
}

// ---------------------------------------------------------------------------
extern "C" void kernel_launch(void* const* d_in, const int* in_sizes, int n_in,
                              void* d_out, int out_size, void* d_ws, size_t ws_size,
                              hipStream_t stream) {
    const float* x         = (const float*)d_in[0];
    const float* edge_attr = (const float*)d_in[1];
    const int*   paths2    = (const int*)d_in[2];
    const int*   ei2       = (const int*)d_in[3];
    const int*   paths3    = (const int*)d_in[4];
    const int*   ei3       = (const int*)d_in[5];
    const int*   batch     = (const int*)d_in[6];
    const float* w_feat    = (const float*)d_in[7];
    const float* b_feat    = (const float*)d_in[8];
    const float* w_bond    = (const float*)d_in[9];
    const float* b_bond    = (const float*)d_in[10];
    const float* w_ih      = (const float*)d_in[11];
    const float* w_hh      = (const float*)d_in[12];
    const float* b_ih      = (const float*)d_in[13];
    const float* b_hh      = (const float*)d_in[14];
    const float* bn_g      = (const float*)d_in[15];
    const float* bn_b      = (const float*)d_in[16];
    const float* mlp_w1    = (const float*)d_in[17];
    const float* mlp_b1    = (const float*)d_in[18];
    const float* bn1_g     = (const float*)d_in[19];
    const float* bn1_b     = (const float*)d_in[20];
    const float* mlp_w2    = (const float*)d_in[21];
    const float* mlp_b2    = (const float*)d_in[22];
    const float* bn2_g     = (const float*)d_in[23];
    const float* bn2_b     = (const float*)d_in[24];
    const float* w_att     = (const float*)d_in[25];
    const float* b_att     = (const float*)d_in[26];
    const float* w_l1      = (const float*)d_in[27];
    const float* b_l1      = (const float*)d_in[28];
    const float* w_l2      = (const float*)d_in[29];
    const float* b_l2      = (const float*)d_in[30];

    const size_t N64 = (size_t)NNODES * 64;
    float* ws = (float*)d_ws;
    float* W0     = ws;                               // N*64 f32
    float* W1     = W0 + N64;                         // N*64 f32
    float* W2     = W1 + N64;                         // N*64 f32
    float* Wtmp   = W2 + N64;                         // N*64 f32
    float* hsum1  = Wtmp + N64;                       // N*64 f32
    float* hsum2  = hsum1 + N64;                      // N*64 f32
    unsigned short* W0b  = (unsigned short*)(hsum2 + N64);  // N*64 bf16
    unsigned short* Winb = W0b + N64;                       // N*64 bf16
    unsigned short* eab  = Winb + N64;                      // E*64 bf16
    unsigned short* Bp   = eab + (size_t)NEDGES * 64;       // 6*16*64*8 bf16
    float* bsum   = (float*)(Bp + 6 * 16 * 64 * 8);   // 256
    float* st     = bsum + 256;                       // 768
    float* atts   = st + 768;                         // 128
    float* watt   = atts + 128;                       // 64 (2 used)
    float* pooled = watt + 64;                        // G*64

    // ---- prep: zero hsum1+hsum2 and st..pooled; bsum; Bp
    {
        long nzeroA4 = (long)(2 * N64) / 4;
        long nzeroB = 768 + 128 + 64 + (long)NG * 64;
        prep_all<<<2048, 256, 0, stream>>>(b_ih, b_hh, w_ih, w_hh, bsum, Bp,
                                           hsum1, nzeroA4, st, nzeroB);
    }
    encode_all<<<(int)(((size_t)(NNODES + NEDGES) * 16 + 255) / 256), 256, 0, stream>>>(
        x, w_feat, b_feat, edge_attr, w_bond, b_bond, W0, W0b, eab);

    // ---------------- conv 1 (L=2) ----------------
    conv_mfma<2><<<(NP2 + 63) / 64, 256, 0, stream>>>(W0b, eab, paths2, ei2, Bp, bsum, hsum1, NP2);

    col_stats<<<1024, 256, 0, stream>>>(hsum1, NNODES, st + 0);
    gemm64<false, true><<<(NNODES + 63) / 64, 256, 0, stream>>>(hsum1, st + 0, bn_g + 0, bn_b + 0, mlp_w1, mlp_b1, Wtmp, st + 128, NNODES);
    gemm64<true, true><<<(NNODES + 63) / 64, 256, 0, stream>>>(Wtmp, st + 128, bn1_g + 0, bn1_b + 0, mlp_w2, mlp_b2, W1, st + 256, NNODES);
    bn_apply1<<<(int)(((size_t)NNODES * 16 + 255) / 256), 256, 0, stream>>>(W1, st + 256, bn2_g + 0, bn2_b + 0, W0, Winb);

    // ---------------- conv 2 (L=3) ----------------
    conv_mfma<3><<<(NP3 + 63) / 64, 256, 0, stream>>>(Winb, eab, paths3, ei3, Bp, bsum, hsum2, NP3);

    col_stats<<<1024, 256, 0, stream>>>(hsum2, NNODES, st + 384);
    gemm64<false, true><<<(NNODES + 63) / 64, 256, 0, stream>>>(hsum2, st + 384, bn_g + 64, bn_b + 64, mlp_w1 + 4096, mlp_b1 + 64, Wtmp, st + 512, NNODES);
    gemm64<true, true><<<(NNODES + 63) / 64, 256, 0, stream>>>(Wtmp, st + 512, bn1_g + 64, bn1_b + 64, mlp_w2 + 4096, mlp_b2 + 64, W2, st + 640, NNODES);
    bn_apply_att<<<1024, 256, 0, stream>>>(W2, st + 640, bn2_g + 64, bn2_b + 64, W0, W1, atts, NNODES);

    // ---------------- attention + pooling + head ----------------
    att_softmax<<<1, 64, 0, stream>>>(atts, w_att, b_att, watt);
    pool_rep<<<(NNODES + PROWS - 1) / PROWS, 256, 0, stream>>>(W0, W1, W2, watt, batch, pooled, NNODES);
    head_kernel<<<NG / 64, 256, 0, stream>>>(pooled, w_l1, b_l1, w_l2, b_l2, (float*)d_out);
}